// Round 8
// baseline (548.847 us; speedup 1.0000x reference)
//
#include <hip/hip_runtime.h>

#define NN 50000
#define NE 800000
#define NG 64
#define EPSF 1e-5f

typedef __bf16 bf16x8 __attribute__((ext_vector_type(8)));
typedef float f32x4 __attribute__((ext_vector_type(4)));

#define AS1 __attribute__((address_space(1)))
#define AS3 __attribute__((address_space(3)))

__device__ __forceinline__ void gl_lds16(const unsigned short* g, unsigned short* l) {
#if __has_builtin(__builtin_amdgcn_global_load_lds)
  __builtin_amdgcn_global_load_lds((const AS1 void*)g, (AS3 void*)l, 16, 0, 0);
#else
  *(uint4*)l = *(const uint4*)g;
#endif
}

__device__ __forceinline__ unsigned short f2bf(float f) {
  unsigned u = __builtin_bit_cast(unsigned, f);
  u += 0x7fff + ((u >> 16) & 1);  // RNE
  return (unsigned short)(u >> 16);
}
__device__ __forceinline__ float bf_lo(unsigned u) {
  return __builtin_bit_cast(float, u << 16);
}
__device__ __forceinline__ float bf_hi(unsigned u) {
  return __builtin_bit_cast(float, u & 0xffff0000u);
}

// ---------------- fused prep: deg+rank atomics | x->bf16 | weights->bf16^T ----------------
#define DEGB 3125   // = NE/256
#define XB   6250   // = NN*128/4/256
#define WTB  1024   // = 262144/256
__global__ void prep_kernel(const int* __restrict__ src, const int* __restrict__ dst,
                            int* __restrict__ dout, int* __restrict__ din,
                            int* __restrict__ rank,
                            const float* __restrict__ x, unsigned short* __restrict__ xb,
                            const float* __restrict__ W1, const float* __restrict__ Wfc,
                            const float* __restrict__ W2, const float* __restrict__ W3,
                            unsigned short* __restrict__ W1t, unsigned short* __restrict__ Wfct,
                            unsigned short* __restrict__ W2t, unsigned short* __restrict__ W3t) {
  int b = blockIdx.x;
  if (b < DEGB) {
    int e = b * 256 + threadIdx.x;
    atomicAdd(&dout[src[e]], 1);
    rank[e] = atomicAdd(&din[dst[e]], 1);
  } else if (b < DEGB + XB) {
    int i = (b - DEGB) * 256 + threadIdx.x;
    float4 v = ((const float4*)x)[i];
    uint2 pk;
    pk.x = (unsigned)f2bf(v.x) | ((unsigned)f2bf(v.y) << 16);
    pk.y = (unsigned)f2bf(v.z) | ((unsigned)f2bf(v.w) << 16);
    ((uint2*)xb)[i] = pk;
  } else {
    int i = (b - DEGB - XB) * 256 + threadIdx.x;  // 0..262143
    const float* W; unsigned short* Wt; int K, local;
    if (i < 32768)       { W = W1;  Wt = W1t;  K = 128; local = i; }
    else if (i < 65536)  { W = Wfc; Wt = Wfct; K = 128; local = i - 32768; }
    else if (i < 196608) { W = W2;  Wt = W2t;  K = 512; local = i - 65536; }
    else                 { W = W3;  Wt = W3t;  K = 256; local = i - 196608; }
    int n = local / K, k = local - n * K;
    Wt[local] = f2bf(W[(size_t)k * 256 + n]);
  }
}

// ---------------- norms + scan phase 1 ----------------
__global__ void norms_scan1(const int* __restrict__ dout, const int* __restrict__ din,
                            float* __restrict__ onorm, float* __restrict__ inorm,
                            int* __restrict__ bsum, int n) {
  int i = blockIdx.x * 256 + threadIdx.x;
  int d = 0;
  if (i < n) {
    int a = dout[i];
    d = din[i];
    onorm[i] = rsqrtf((float)(a > 1 ? a : 1));
    inorm[i] = rsqrtf((float)(d > 1 ? d : 1));
  }
  int v = d;
#pragma unroll
  for (int off = 32; off > 0; off >>= 1) v += __shfl_down(v, off);
  __shared__ int ws[4];
  int wave = threadIdx.x >> 6, lane = threadIdx.x & 63;
  if (lane == 0) ws[wave] = v;
  __syncthreads();
  if (threadIdx.x == 0) bsum[blockIdx.x] = ws[0] + ws[1] + ws[2] + ws[3];
}

__global__ void scan2_kernel(const int* __restrict__ bsum, int* __restrict__ boff,
                             int nb, int* __restrict__ rp, int n) {
  int t = threadIdx.x;
  int v = (t < nb) ? bsum[t] : 0;
  __shared__ int tmp[256];
  tmp[t] = v;
  __syncthreads();
  for (int off = 1; off < 256; off <<= 1) {
    int x = (t >= off) ? tmp[t - off] : 0;
    __syncthreads();
    tmp[t] += x;
    __syncthreads();
  }
  if (t < nb) boff[t] = tmp[t] - v;
  if (t == 255) rp[n] = tmp[255];
}

__global__ void scan3_kernel(const int* __restrict__ din, const int* __restrict__ boff,
                             int* __restrict__ rp, int n) {
  int t = threadIdx.x;
  int i = blockIdx.x * 256 + t;
  int v = (i < n) ? din[i] : 0;
  __shared__ int tmp[256];
  tmp[t] = v;
  __syncthreads();
  for (int off = 1; off < 256; off <<= 1) {
    int x = (t >= off) ? tmp[t - off] : 0;
    __syncthreads();
    tmp[t] += x;
    __syncthreads();
  }
  if (i < n) rp[i] = tmp[t] - v + boff[blockIdx.x];
}

// ---------------- CSR fill, atomic-free ----------------
__global__ void fill_kernel(const int* __restrict__ src, const int* __restrict__ dst,
                            const float* __restrict__ w, const float* __restrict__ onorm,
                            const float* __restrict__ inorm,
                            const int* __restrict__ rp, const int* __restrict__ rank,
                            int* __restrict__ col, float* __restrict__ wse, int E) {
  int e = blockIdx.x * 256 + threadIdx.x;
  if (e < E) {
    int d = dst[e], s = src[e];
    int pos = rp[d] + rank[e];
    col[pos] = s;
    wse[pos] = w[e] * onorm[s] * inorm[d];
  }
}

// ---------------- SpMM v3: 128-col slice, 16 edges in flight per wave ----------------
// One wave per dst node (4 nodes/block). G=16 lanes cover the 128-col slice
// (16 lanes x 8 bf16 = 128); grp = lane/16 in 0..3 handles edge ed = e + u*4 + grp.
template <int RELU>
__global__ __launch_bounds__(256) void spmm_v3(
    const unsigned short* __restrict__ feat, int ldf,   // pre-offset to slice
    const int* __restrict__ rp, const int* __restrict__ col,
    const float* __restrict__ wse,
    unsigned short* __restrict__ out, int ldo, int nNodes) {
  const int wv = threadIdx.x >> 6;
  const int lane = threadIdx.x & 63;
  const int v = blockIdx.x * 4 + wv;
  if (v >= nNodes) return;
  const int grp = lane >> 4;   // 0..3
  const int c = lane & 15;     // 0..15
  const int beg = rp[v], end = rp[v + 1];
  float acc[8];
#pragma unroll
  for (int k = 0; k < 8; k++) acc[k] = 0.f;
  const unsigned short* fbase = feat + c * 8;
  for (int e = beg; e < end; e += 16) {
#pragma unroll
    for (int u = 0; u < 4; u++) {
      int ed = e + u * 4 + grp;
      if (ed < end) {
        int s = col[ed];
        float wgt = wse[ed];
        uint4 q = *(const uint4*)&fbase[(size_t)s * ldf];
        acc[0] += wgt * bf_lo(q.x); acc[1] += wgt * bf_hi(q.x);
        acc[2] += wgt * bf_lo(q.y); acc[3] += wgt * bf_hi(q.y);
        acc[4] += wgt * bf_lo(q.z); acc[5] += wgt * bf_hi(q.z);
        acc[6] += wgt * bf_lo(q.w); acc[7] += wgt * bf_hi(q.w);
      }
    }
  }
  // combine the 4 edge groups: lanes {c,16+c,32+c,48+c} hold partials
#pragma unroll
  for (int k = 0; k < 8; k++) acc[k] += __shfl_xor(acc[k], 32);
#pragma unroll
  for (int k = 0; k < 8; k++) acc[k] += __shfl_xor(acc[k], 16);
  if (grp == 0) {
    unsigned o[4];
#pragma unroll
    for (int j = 0; j < 4; j++) {
      float a = acc[2 * j], b = acc[2 * j + 1];
      if (RELU) { a = fmaxf(a, 0.f); b = fmaxf(b, 0.f); }
      o[j] = (unsigned)f2bf(a) | ((unsigned)f2bf(b) << 16);
    }
    *(uint4*)&out[(size_t)v * ldo + c * 8] = make_uint4(o[0], o[1], o[2], o[3]);
  }
}

// ---------------- MFMA GEMM body: 128-K panels, 64 MFMAs between barriers ----------------
// 128x128 tile, 4 waves (2x2), each wave 4x4 16x16x32 tiles. LDS 64 KB.
__device__ __forceinline__ void gemm_body(
    const unsigned short* __restrict__ A, int lda,
    const unsigned short* __restrict__ Bt, int K,
    void* __restrict__ Cv, int ldc, int col_off, int M,
    int relu, int out32,
    unsigned short* As, unsigned short* Bs) {
  const int tid = threadIdx.x;
  const int lane = tid & 63;
  const int w = tid >> 6;
  const int wm = w >> 1, wn = w & 1;
  const int m0 = blockIdx.x * 128;
  const int n0 = blockIdx.y * 128;
  const int q = lane >> 4;
  const int r16 = lane & 15;

  f32x4 acc[4][4];
#pragma unroll
  for (int i = 0; i < 4; i++)
#pragma unroll
    for (int j = 0; j < 4; j++) acc[i][j] = (f32x4){0.f, 0.f, 0.f, 0.f};

  const int ta = 2 * w, tb = 2 * w + 1;
  int gma = m0 + ta * 16 + r16; if (gma >= M) gma = M - 1;
  int gmb = m0 + tb * 16 + r16; if (gmb >= M) gmb = M - 1;
  const int gna = n0 + ta * 16 + r16;
  const int gnb = n0 + tb * 16 + r16;
  const unsigned short* pa = A + (size_t)gma * lda + q * 8;
  const unsigned short* pb = A + (size_t)gmb * lda + q * 8;
  const unsigned short* pc = Bt + (size_t)gna * K + q * 8;
  const unsigned short* pd = Bt + (size_t)gnb * K + q * 8;

  for (int kp = 0; kp < K; kp += 128) {
    __syncthreads();  // prior panel's ds_reads complete
    // stage full 128-K panel: 4 chunks x (2 A-tiles + 2 B-tiles) per wave
#pragma unroll
    for (int c = 0; c < 4; c++) {
      gl_lds16(pa + kp + c * 32, &As[(c * 8 + ta) * 512 + lane * 8]);
      gl_lds16(pb + kp + c * 32, &As[(c * 8 + tb) * 512 + lane * 8]);
      gl_lds16(pc + kp + c * 32, &Bs[(c * 8 + ta) * 512 + lane * 8]);
      gl_lds16(pd + kp + c * 32, &Bs[(c * 8 + tb) * 512 + lane * 8]);
    }
    __syncthreads();  // staging drained

#pragma unroll
    for (int c = 0; c < 4; c++) {
      bf16x8 af[4], bfr[4];
#pragma unroll
      for (int i = 0; i < 4; i++)
        af[i] = *(const bf16x8*)&As[(c * 8 + wm * 4 + i) * 512 + lane * 8];
#pragma unroll
      for (int j = 0; j < 4; j++)
        bfr[j] = *(const bf16x8*)&Bs[(c * 8 + wn * 4 + j) * 512 + lane * 8];
#pragma unroll
      for (int i = 0; i < 4; i++)
#pragma unroll
        for (int j = 0; j < 4; j++)
          acc[i][j] = __builtin_amdgcn_mfma_f32_16x16x32_bf16(af[i], bfr[j], acc[i][j], 0, 0, 0);
    }
  }

#pragma unroll
  for (int i = 0; i < 4; i++) {
    int rbase = m0 + (wm * 4 + i) * 16 + q * 4;
#pragma unroll
    for (int r = 0; r < 4; r++) {
      int gm = rbase + r;
      if (gm >= M) continue;
#pragma unroll
      for (int j = 0; j < 4; j++) {
        float v = acc[i][j][r];
        if (relu) v = fmaxf(v, 0.f);
        int gn = col_off + n0 + (wn * 4 + j) * 16 + r16;
        if (out32)
          ((float*)Cv)[(size_t)gm * ldc + gn] = v;
        else
          ((unsigned short*)Cv)[(size_t)gm * ldc + gn] = f2bf(v);
      }
    }
  }
}

// fused conv1-GEMM (z=0) + fc-GEMM (z=1)
__global__ __launch_bounds__(256) void gemm12_kernel(
    const unsigned short* __restrict__ A0, const unsigned short* __restrict__ B0,
    const unsigned short* __restrict__ A1, const unsigned short* __restrict__ B1,
    unsigned short* __restrict__ C, int M) {
  __shared__ unsigned short As[32 * 512];  // 32 KB
  __shared__ unsigned short Bs[32 * 512];  // 32 KB
  int z = blockIdx.z;
  gemm_body(z ? A1 : A0, 128, z ? B1 : B0, 128, C, 512, z * 256, M, z == 0, 0, As, Bs);
}

__global__ __launch_bounds__(256) void gemm_kernel(
    const unsigned short* __restrict__ A, int lda,
    const unsigned short* __restrict__ Bt, int K,
    void* __restrict__ Cv, int ldc, int M, int relu, int out32) {
  __shared__ unsigned short As[32 * 512];
  __shared__ unsigned short Bs[32 * 512];
  gemm_body(A, lda, Bt, K, Cv, ldc, 0, M, relu, out32, As, Bs);
}

// ---------------- LayerNorm + relu (bf16 in/out, fp32 stats) ----------------
__global__ void ln_relu_bf16(unsigned short* __restrict__ h, int ld,
                             const float* __restrict__ gamma,
                             const float* __restrict__ beta) {
  int v = blockIdx.x;
  int f = threadIdx.x;  // 256
  float val = bf_lo((unsigned)h[(size_t)v * ld + f]);
  float s = val, qq = val * val;
#pragma unroll
  for (int off = 32; off > 0; off >>= 1) {
    s += __shfl_down(s, off);
    qq += __shfl_down(qq, off);
  }
  __shared__ float ws_[5], wq_[5];
  int wave = f >> 6, lane = f & 63;
  if (lane == 0) { ws_[wave] = s; wq_[wave] = qq; }
  __syncthreads();
  if (f == 0) {
    float S = 0, Q = 0;
    for (int i = 0; i < 4; i++) { S += ws_[i]; Q += wq_[i]; }
    ws_[4] = S; wq_[4] = Q;
  }
  __syncthreads();
  float mean = ws_[4] * (1.f / 256.f);
  float var = wq_[4] * (1.f / 256.f) - mean * mean;
  float y = (val - mean) * rsqrtf(var + EPSF) * gamma[f] + beta[f];
  h[(size_t)v * ld + f] = f2bf(y > 0.f ? y : 0.f);
}

// ---------------- per-graph readout (graph_ids sorted), x3 fp32 ----------------
__global__ void readout_kernel(const float* __restrict__ x3, const int* __restrict__ gid,
                               float* __restrict__ out, int n) {
  int g = blockIdx.x;
  int part = blockIdx.y;  // 8 parts
  int f = threadIdx.x;    // 256
  int lo = 0, hi = n;
  while (lo < hi) { int mid = (lo + hi) >> 1; if (gid[mid] < g) lo = mid + 1; else hi = mid; }
  int s = lo;
  lo = s; hi = n;
  while (lo < hi) { int mid = (lo + hi) >> 1; if (gid[mid] < g + 1) lo = mid + 1; else hi = mid; }
  int e = lo;
  int len = e - s;
  if (len <= 0) return;
  int chunk = (len + 7) / 8;
  int cs = s + part * chunk;
  int ce = cs + chunk; if (ce > e) ce = e;
  if (cs >= ce) return;
  float acc = 0.f;
  for (int v = cs; v < ce; v++) acc += x3[(size_t)v * 256 + f];
  atomicAdd(&out[g * 256 + f], acc);
}

// ---------------- launch ----------------

extern "C" void kernel_launch(void* const* d_in, const int* in_sizes, int n_in,
                              void* d_out, int out_size, void* d_ws, size_t ws_size,
                              hipStream_t stream) {
  const float* x     = (const float*)d_in[0];
  const float* w     = (const float*)d_in[1];
  const float* W1    = (const float*)d_in[2];
  const float* Wfc   = (const float*)d_in[3];
  const float* gamma = (const float*)d_in[4];
  const float* beta  = (const float*)d_in[5];
  const float* W2    = (const float*)d_in[6];
  const float* W3    = (const float*)d_in[7];
  const int*   src   = (const int*)d_in[8];
  const int*   dst   = (const int*)d_in[9];
  const int*   gid   = (const int*)d_in[10];
  float* out = (float*)d_out;

  const int N = NN, E = NE;

  char* p = (char*)d_ws;
  auto alloc = [&](size_t bytes) {
    char* r = p;
    p += (bytes + 255) & ~(size_t)255;
    return r;
  };
  int*   deg_out = (int*)alloc((size_t)N * 4);
  int*   deg_in  = (int*)alloc((size_t)N * 4);   // contiguous after deg_out
  float* onorm   = (float*)alloc((size_t)N * 4);
  float* inorm   = (float*)alloc((size_t)N * 4);
  int*   row_ptr = (int*)alloc((size_t)(N + 1) * 4);
  int*   bsum    = (int*)alloc(256 * 4);
  int*   boff    = (int*)alloc(256 * 4);
  int*   rank    = (int*)alloc((size_t)E * 4);
  int*   col     = (int*)alloc((size_t)E * 4);
  float* wse     = (float*)alloc((size_t)E * 4);
  unsigned short* xb    = (unsigned short*)alloc((size_t)N * 128 * 2);
  unsigned short* aggX  = (unsigned short*)alloc((size_t)N * 128 * 2);
  unsigned short* x1f1  = (unsigned short*)alloc((size_t)N * 512 * 2);
  unsigned short* y2    = (unsigned short*)alloc((size_t)N * 256 * 2);
  unsigned short* x2    = (unsigned short*)alloc((size_t)N * 256 * 2);
  unsigned short* aggx2 = (unsigned short*)alloc((size_t)N * 256 * 2);
  unsigned short* W1t   = (unsigned short*)alloc((size_t)256 * 128 * 2);
  unsigned short* Wfct  = (unsigned short*)alloc((size_t)256 * 128 * 2);
  unsigned short* W2t   = (unsigned short*)alloc((size_t)256 * 512 * 2);
  unsigned short* W3t   = (unsigned short*)alloc((size_t)256 * 256 * 2);
  float* x3 = (float*)x1f1;  // x1f1 dead after y2 GEMM; reuse storage

  hipMemsetAsync(deg_out, 0, (size_t)((char*)onorm - (char*)deg_out), stream);
  hipMemsetAsync(out, 0, (size_t)NG * 256 * 4, stream);

  const int nbS = (N + 255) / 256;  // 196

  prep_kernel<<<DEGB + XB + WTB, 256, 0, stream>>>(src, dst, deg_out, deg_in, rank,
                                                   x, xb, W1, Wfc, W2, W3,
                                                   W1t, Wfct, W2t, W3t);
  norms_scan1<<<nbS, 256, 0, stream>>>(deg_out, deg_in, onorm, inorm, bsum, N);
  scan2_kernel<<<1, 256, 0, stream>>>(bsum, boff, nbS, row_ptr, N);
  scan3_kernel<<<nbS, 256, 0, stream>>>(deg_in, boff, row_ptr, N);
  fill_kernel<<<(E + 255) / 256, 256, 0, stream>>>(src, dst, w, onorm, inorm, row_ptr,
                                                   rank, col, wse, E);

  dim3 ggrid((N + 127) / 128, 2);       // 391 x 2
  dim3 ggridz((N + 127) / 128, 2, 2);   // 391 x 2 x 2 (z: which GEMM)
  const int spGrid = (N + 3) / 4;       // 12500

  // aggX' = agg(xb)  [norms folded into wse], single 128-col slice
  spmm_v3<0><<<spGrid, 256, 0, stream>>>(xb, 128, row_ptr, col, wse, aggX, 128, N);
  // z=0: x1 = relu(aggX'@W1) -> x1f1[:,0:256] ; z=1: f1pre = xb@Wfc -> x1f1[:,256:512]
  gemm12_kernel<<<ggridz, 256, 0, stream>>>(aggX, W1t, xb, Wfct, x1f1, N);
  // f1 = relu(LN(f1pre)) in place
  ln_relu_bf16<<<N, 256, 0, stream>>>(x1f1 + 256, 512, gamma, beta);
  // y2 = x1f1 @ W2
  gemm_kernel<<<ggrid, 256, 0, stream>>>(x1f1, 512, W2t, 512, y2, 256, N, 0, 0);
  // x2 = relu(agg'(y2)), two 128-col slices (better L2 residency + MLP)
  spmm_v3<1><<<spGrid, 256, 0, stream>>>(y2, 256, row_ptr, col, wse, x2, 256, N);
  spmm_v3<1><<<spGrid, 256, 0, stream>>>(y2 + 128, 256, row_ptr, col, wse, x2 + 128, 256, N);
  // aggx2 = agg'(x2), two slices
  spmm_v3<0><<<spGrid, 256, 0, stream>>>(x2, 256, row_ptr, col, wse, aggx2, 256, N);
  spmm_v3<0><<<spGrid, 256, 0, stream>>>(x2 + 128, 256, row_ptr, col, wse, aggx2 + 128, 256, N);
  // x3 = relu(aggx2 @ W3) fp32
  gemm_kernel<<<ggrid, 256, 0, stream>>>(aggx2, 256, W3t, 256, x3, 256, N, 1, 1);
  // readout
  readout_kernel<<<dim3(NG, 8), 256, 0, stream>>>(x3, gid, out, N);
}

// Round 9
// 522.552 us; speedup vs baseline: 1.0503x; 1.0503x over previous
//
#include <hip/hip_runtime.h>

#define NN 50000
#define NE 800000
#define NG 64
#define EPSF 1e-5f

typedef __bf16 bf16x8 __attribute__((ext_vector_type(8)));
typedef float f32x4 __attribute__((ext_vector_type(4)));

#define AS1 __attribute__((address_space(1)))
#define AS3 __attribute__((address_space(3)))

__device__ __forceinline__ void gl_lds16(const unsigned short* g, unsigned short* l) {
#if __has_builtin(__builtin_amdgcn_global_load_lds)
  __builtin_amdgcn_global_load_lds((const AS1 void*)g, (AS3 void*)l, 16, 0, 0);
#else
  *(uint4*)l = *(const uint4*)g;
#endif
}

__device__ __forceinline__ unsigned short f2bf(float f) {
  unsigned u = __builtin_bit_cast(unsigned, f);
  u += 0x7fff + ((u >> 16) & 1);  // RNE
  return (unsigned short)(u >> 16);
}
__device__ __forceinline__ float bf_lo(unsigned u) {
  return __builtin_bit_cast(float, u << 16);
}
__device__ __forceinline__ float bf_hi(unsigned u) {
  return __builtin_bit_cast(float, u & 0xffff0000u);
}

// ---------------- fused prep: deg+rank atomics | x->bf16 | weights->bf16^T ----------------
// Atomic blocks are fabric-RMW-rate-bound (~1% VALU, ~12% HBM); cvt blocks ride
// in their shadow. [measured R7: 85 us ~= standalone deg_rank, cvt hidden]
#define DEGB 3125   // = NE/256
#define XB   6250   // = NN*128/4/256
#define WTB  1024   // = 262144/256
__global__ void prep_kernel(const int* __restrict__ src, const int* __restrict__ dst,
                            int* __restrict__ dout, int* __restrict__ din,
                            int* __restrict__ rank,
                            const float* __restrict__ x, unsigned short* __restrict__ xb,
                            const float* __restrict__ W1, const float* __restrict__ Wfc,
                            const float* __restrict__ W2, const float* __restrict__ W3,
                            unsigned short* __restrict__ W1t, unsigned short* __restrict__ Wfct,
                            unsigned short* __restrict__ W2t, unsigned short* __restrict__ W3t) {
  int b = blockIdx.x;
  if (b < DEGB) {
    int e = b * 256 + threadIdx.x;
    atomicAdd(&dout[src[e]], 1);
    rank[e] = atomicAdd(&din[dst[e]], 1);
  } else if (b < DEGB + XB) {
    int i = (b - DEGB) * 256 + threadIdx.x;
    float4 v = ((const float4*)x)[i];
    uint2 pk;
    pk.x = (unsigned)f2bf(v.x) | ((unsigned)f2bf(v.y) << 16);
    pk.y = (unsigned)f2bf(v.z) | ((unsigned)f2bf(v.w) << 16);
    ((uint2*)xb)[i] = pk;
  } else {
    int i = (b - DEGB - XB) * 256 + threadIdx.x;  // 0..262143
    const float* W; unsigned short* Wt; int K, local;
    if (i < 32768)       { W = W1;  Wt = W1t;  K = 128; local = i; }
    else if (i < 65536)  { W = Wfc; Wt = Wfct; K = 128; local = i - 32768; }
    else if (i < 196608) { W = W2;  Wt = W2t;  K = 512; local = i - 65536; }
    else                 { W = W3;  Wt = W3t;  K = 256; local = i - 196608; }
    int n = local / K, k = local - n * K;
    Wt[local] = f2bf(W[(size_t)k * 256 + n]);
  }
}

// ---------------- norms + scan phase 1 ----------------
__global__ void norms_scan1(const int* __restrict__ dout, const int* __restrict__ din,
                            float* __restrict__ onorm, float* __restrict__ inorm,
                            int* __restrict__ bsum, int n) {
  int i = blockIdx.x * 256 + threadIdx.x;
  int d = 0;
  if (i < n) {
    int a = dout[i];
    d = din[i];
    onorm[i] = rsqrtf((float)(a > 1 ? a : 1));
    inorm[i] = rsqrtf((float)(d > 1 ? d : 1));
  }
  int v = d;
#pragma unroll
  for (int off = 32; off > 0; off >>= 1) v += __shfl_down(v, off);
  __shared__ int ws[4];
  int wave = threadIdx.x >> 6, lane = threadIdx.x & 63;
  if (lane == 0) ws[wave] = v;
  __syncthreads();
  if (threadIdx.x == 0) bsum[blockIdx.x] = ws[0] + ws[1] + ws[2] + ws[3];
}

__global__ void scan2_kernel(const int* __restrict__ bsum, int* __restrict__ boff,
                             int nb, int* __restrict__ rp, int n) {
  int t = threadIdx.x;
  int v = (t < nb) ? bsum[t] : 0;
  __shared__ int tmp[256];
  tmp[t] = v;
  __syncthreads();
  for (int off = 1; off < 256; off <<= 1) {
    int x = (t >= off) ? tmp[t - off] : 0;
    __syncthreads();
    tmp[t] += x;
    __syncthreads();
  }
  if (t < nb) boff[t] = tmp[t] - v;
  if (t == 255) rp[n] = tmp[255];
}

__global__ void scan3_kernel(const int* __restrict__ din, const int* __restrict__ boff,
                             int* __restrict__ rp, int n) {
  int t = threadIdx.x;
  int i = blockIdx.x * 256 + t;
  int v = (i < n) ? din[i] : 0;
  __shared__ int tmp[256];
  tmp[t] = v;
  __syncthreads();
  for (int off = 1; off < 256; off <<= 1) {
    int x = (t >= off) ? tmp[t - off] : 0;
    __syncthreads();
    tmp[t] += x;
    __syncthreads();
  }
  if (i < n) rp[i] = tmp[t] - v + boff[blockIdx.x];
}

// ---------------- CSR fill, atomic-free; wse = w * onorm[src] * inorm[dst] ----------------
__global__ void fill_kernel(const int* __restrict__ src, const int* __restrict__ dst,
                            const float* __restrict__ w, const float* __restrict__ onorm,
                            const float* __restrict__ inorm,
                            const int* __restrict__ rp, const int* __restrict__ rank,
                            int* __restrict__ col, float* __restrict__ wse, int E) {
  int e = blockIdx.x * 256 + threadIdx.x;
  if (e < E) {
    int d = dst[e], s = src[e];
    int pos = rp[d] + rank[e];
    col[pos] = s;
    wse[pos] = w[e] * onorm[s] * inorm[d];
  }
}

// ---------------- SpMM (best-known R5 form + 8-edge unroll) ----------------
// one 64-thread block per dst node; NU uints (=2*NU feats) per thread.
// col/wse indices are wave-uniform -> scalar loads; 8 edges => up to 16
// independent gathers in flight per lane.
template <int RELU, int NU>
__global__ __launch_bounds__(64) void spmm_bf16(
    const unsigned short* __restrict__ feat, int ldf,
    const int* __restrict__ rp, const int* __restrict__ col,
    const float* __restrict__ wse,
    unsigned short* __restrict__ out, int ldo) {
  int v = blockIdx.x;
  int t = threadIdx.x;  // 64
  int beg = rp[v], end = rp[v + 1];
  float acc[2 * NU];
#pragma unroll
  for (int i = 0; i < 2 * NU; i++) acc[i] = 0.f;
  const unsigned short* base = feat + t * (2 * NU);
  int e = beg;
  for (; e + 8 <= end; e += 8) {
    int s[8]; float ww[8];
#pragma unroll
    for (int k = 0; k < 8; k++) { s[k] = col[e + k]; ww[k] = wse[e + k]; }
    unsigned u[8][NU];
#pragma unroll
    for (int k = 0; k < 8; k++) {
      const unsigned* pr = (const unsigned*)&base[(size_t)s[k] * ldf];
      if (NU == 2) { uint2 q = *(const uint2*)pr; u[k][0] = q.x; u[k][NU - 1] = q.y; }
      else u[k][0] = pr[0];
    }
#pragma unroll
    for (int k = 0; k < 8; k++)
#pragma unroll
      for (int j = 0; j < NU; j++) {
        acc[2 * j]     += ww[k] * bf_lo(u[k][j]);
        acc[2 * j + 1] += ww[k] * bf_hi(u[k][j]);
      }
  }
  for (; e < end; e++) {
    float w0 = wse[e];
    const unsigned* pr = (const unsigned*)&base[(size_t)col[e] * ldf];
    unsigned u[NU];
    if (NU == 2) { uint2 q = *(const uint2*)pr; u[0] = q.x; u[NU - 1] = q.y; }
    else u[0] = pr[0];
#pragma unroll
    for (int j = 0; j < NU; j++) {
      acc[2 * j]     += w0 * bf_lo(u[j]);
      acc[2 * j + 1] += w0 * bf_hi(u[j]);
    }
  }
  unsigned o[NU];
#pragma unroll
  for (int j = 0; j < NU; j++) {
    float a = acc[2 * j], b = acc[2 * j + 1];
    if (RELU) { a = fmaxf(a, 0.f); b = fmaxf(b, 0.f); }
    o[j] = (unsigned)f2bf(a) | ((unsigned)f2bf(b) << 16);
  }
  unsigned* po = (unsigned*)&out[(size_t)v * ldo + t * (2 * NU)];
  if (NU == 2) *(uint2*)po = make_uint2(o[0], o[NU - 1]);
  else po[0] = o[0];
}

// ---------------- MFMA GEMM body: BK=32 (proven R5/R7 form) ----------------
// 128x128 tile, 4 waves (2x2), each wave 4x4 16x16x32 tiles, LDS 16 KB.
__device__ __forceinline__ void gemm_body(
    const unsigned short* __restrict__ A, int lda,
    const unsigned short* __restrict__ Bt, int K,
    void* __restrict__ Cv, int ldc, int col_off, int M,
    int relu, int out32,
    unsigned short* As, unsigned short* Bs) {
  const int tid = threadIdx.x;
  const int lane = tid & 63;
  const int w = tid >> 6;
  const int wm = w >> 1, wn = w & 1;
  const int m0 = blockIdx.x * 128;
  const int n0 = blockIdx.y * 128;
  const int q = lane >> 4;
  const int r16 = lane & 15;

  f32x4 acc[4][4];
#pragma unroll
  for (int i = 0; i < 4; i++)
#pragma unroll
    for (int j = 0; j < 4; j++) acc[i][j] = (f32x4){0.f, 0.f, 0.f, 0.f};

  const int ta = 2 * w, tb = 2 * w + 1;
  int gma = m0 + ta * 16 + r16; if (gma >= M) gma = M - 1;
  int gmb = m0 + tb * 16 + r16; if (gmb >= M) gmb = M - 1;
  const int gna = n0 + ta * 16 + r16;
  const int gnb = n0 + tb * 16 + r16;
  const unsigned short* pa = A + (size_t)gma * lda + q * 8;
  const unsigned short* pb = A + (size_t)gmb * lda + q * 8;
  const unsigned short* pc = Bt + (size_t)gna * K + q * 8;
  const unsigned short* pd = Bt + (size_t)gnb * K + q * 8;

  for (int k0 = 0; k0 < K; k0 += 32) {
    __syncthreads();
    gl_lds16(pa + k0, &As[ta * 512 + lane * 8]);
    gl_lds16(pb + k0, &As[tb * 512 + lane * 8]);
    gl_lds16(pc + k0, &Bs[ta * 512 + lane * 8]);
    gl_lds16(pd + k0, &Bs[tb * 512 + lane * 8]);
    __syncthreads();

    bf16x8 af[4], bfr[4];
#pragma unroll
    for (int i = 0; i < 4; i++)
      af[i] = *(const bf16x8*)&As[(wm * 4 + i) * 512 + lane * 8];
#pragma unroll
    for (int j = 0; j < 4; j++)
      bfr[j] = *(const bf16x8*)&Bs[(wn * 4 + j) * 512 + lane * 8];
#pragma unroll
    for (int i = 0; i < 4; i++)
#pragma unroll
      for (int j = 0; j < 4; j++)
        acc[i][j] = __builtin_amdgcn_mfma_f32_16x16x32_bf16(af[i], bfr[j], acc[i][j], 0, 0, 0);
  }

#pragma unroll
  for (int i = 0; i < 4; i++) {
    int rbase = m0 + (wm * 4 + i) * 16 + q * 4;
#pragma unroll
    for (int r = 0; r < 4; r++) {
      int gm = rbase + r;
      if (gm >= M) continue;
#pragma unroll
      for (int j = 0; j < 4; j++) {
        float v = acc[i][j][r];
        if (relu) v = fmaxf(v, 0.f);
        int gn = col_off + n0 + (wn * 4 + j) * 16 + r16;
        if (out32)
          ((float*)Cv)[(size_t)gm * ldc + gn] = v;
        else
          ((unsigned short*)Cv)[(size_t)gm * ldc + gn] = f2bf(v);
      }
    }
  }
}

// fused conv1-GEMM (z=0) + fc-GEMM (z=1)
__global__ __launch_bounds__(256) void gemm12_kernel(
    const unsigned short* __restrict__ A0, const unsigned short* __restrict__ B0,
    const unsigned short* __restrict__ A1, const unsigned short* __restrict__ B1,
    unsigned short* __restrict__ C, int M) {
  __shared__ unsigned short As[8 * 512];
  __shared__ unsigned short Bs[8 * 512];
  int z = blockIdx.z;
  gemm_body(z ? A1 : A0, 128, z ? B1 : B0, 128, C, 512, z * 256, M, z == 0, 0, As, Bs);
}

__global__ __launch_bounds__(256) void gemm_kernel(
    const unsigned short* __restrict__ A, int lda,
    const unsigned short* __restrict__ Bt, int K,
    void* __restrict__ Cv, int ldc, int M, int relu, int out32) {
  __shared__ unsigned short As[8 * 512];
  __shared__ unsigned short Bs[8 * 512];
  gemm_body(A, lda, Bt, K, Cv, ldc, 0, M, relu, out32, As, Bs);
}

// ---------------- LayerNorm + relu (bf16 in/out, fp32 stats) ----------------
__global__ void ln_relu_bf16(unsigned short* __restrict__ h, int ld,
                             const float* __restrict__ gamma,
                             const float* __restrict__ beta) {
  int v = blockIdx.x;
  int f = threadIdx.x;  // 256
  float val = bf_lo((unsigned)h[(size_t)v * ld + f]);
  float s = val, qq = val * val;
#pragma unroll
  for (int off = 32; off > 0; off >>= 1) {
    s += __shfl_down(s, off);
    qq += __shfl_down(qq, off);
  }
  __shared__ float ws_[5], wq_[5];
  int wave = f >> 6, lane = f & 63;
  if (lane == 0) { ws_[wave] = s; wq_[wave] = qq; }
  __syncthreads();
  if (f == 0) {
    float S = 0, Q = 0;
    for (int i = 0; i < 4; i++) { S += ws_[i]; Q += wq_[i]; }
    ws_[4] = S; wq_[4] = Q;
  }
  __syncthreads();
  float mean = ws_[4] * (1.f / 256.f);
  float var = wq_[4] * (1.f / 256.f) - mean * mean;
  float y = (val - mean) * rsqrtf(var + EPSF) * gamma[f] + beta[f];
  h[(size_t)v * ld + f] = f2bf(y > 0.f ? y : 0.f);
}

// ---------------- per-graph readout (graph_ids sorted), x3 fp32 ----------------
__global__ void readout_kernel(const float* __restrict__ x3, const int* __restrict__ gid,
                               float* __restrict__ out, int n) {
  int g = blockIdx.x;
  int part = blockIdx.y;  // 8 parts
  int f = threadIdx.x;    // 256
  int lo = 0, hi = n;
  while (lo < hi) { int mid = (lo + hi) >> 1; if (gid[mid] < g) lo = mid + 1; else hi = mid; }
  int s = lo;
  lo = s; hi = n;
  while (lo < hi) { int mid = (lo + hi) >> 1; if (gid[mid] < g + 1) lo = mid + 1; else hi = mid; }
  int e = lo;
  int len = e - s;
  if (len <= 0) return;
  int chunk = (len + 7) / 8;
  int cs = s + part * chunk;
  int ce = cs + chunk; if (ce > e) ce = e;
  if (cs >= ce) return;
  float acc = 0.f;
  for (int v = cs; v < ce; v++) acc += x3[(size_t)v * 256 + f];
  atomicAdd(&out[g * 256 + f], acc);
}

// ---------------- launch ----------------

extern "C" void kernel_launch(void* const* d_in, const int* in_sizes, int n_in,
                              void* d_out, int out_size, void* d_ws, size_t ws_size,
                              hipStream_t stream) {
  const float* x     = (const float*)d_in[0];
  const float* w     = (const float*)d_in[1];
  const float* W1    = (const float*)d_in[2];
  const float* Wfc   = (const float*)d_in[3];
  const float* gamma = (const float*)d_in[4];
  const float* beta  = (const float*)d_in[5];
  const float* W2    = (const float*)d_in[6];
  const float* W3    = (const float*)d_in[7];
  const int*   src   = (const int*)d_in[8];
  const int*   dst   = (const int*)d_in[9];
  const int*   gid   = (const int*)d_in[10];
  float* out = (float*)d_out;

  const int N = NN, E = NE;

  char* p = (char*)d_ws;
  auto alloc = [&](size_t bytes) {
    char* r = p;
    p += (bytes + 255) & ~(size_t)255;
    return r;
  };
  int*   deg_out = (int*)alloc((size_t)N * 4);
  int*   deg_in  = (int*)alloc((size_t)N * 4);   // contiguous after deg_out
  float* onorm   = (float*)alloc((size_t)N * 4);
  float* inorm   = (float*)alloc((size_t)N * 4);
  int*   row_ptr = (int*)alloc((size_t)(N + 1) * 4);
  int*   bsum    = (int*)alloc(256 * 4);
  int*   boff    = (int*)alloc(256 * 4);
  int*   rank    = (int*)alloc((size_t)E * 4);
  int*   col     = (int*)alloc((size_t)E * 4);
  float* wse     = (float*)alloc((size_t)E * 4);
  unsigned short* xb    = (unsigned short*)alloc((size_t)N * 128 * 2);
  unsigned short* aggX  = (unsigned short*)alloc((size_t)N * 128 * 2);
  unsigned short* x1f1  = (unsigned short*)alloc((size_t)N * 512 * 2);
  unsigned short* y2    = (unsigned short*)alloc((size_t)N * 256 * 2);
  unsigned short* x2    = (unsigned short*)alloc((size_t)N * 256 * 2);
  unsigned short* aggx2 = (unsigned short*)alloc((size_t)N * 256 * 2);
  unsigned short* W1t   = (unsigned short*)alloc((size_t)256 * 128 * 2);
  unsigned short* Wfct  = (unsigned short*)alloc((size_t)256 * 128 * 2);
  unsigned short* W2t   = (unsigned short*)alloc((size_t)256 * 512 * 2);
  unsigned short* W3t   = (unsigned short*)alloc((size_t)256 * 256 * 2);
  float* x3 = (float*)x1f1;  // x1f1 dead after y2 GEMM; reuse storage

  hipMemsetAsync(deg_out, 0, (size_t)((char*)onorm - (char*)deg_out), stream);
  hipMemsetAsync(out, 0, (size_t)NG * 256 * 4, stream);

  const int nbS = (N + 255) / 256;  // 196

  prep_kernel<<<DEGB + XB + WTB, 256, 0, stream>>>(src, dst, deg_out, deg_in, rank,
                                                   x, xb, W1, Wfc, W2, W3,
                                                   W1t, Wfct, W2t, W3t);
  norms_scan1<<<nbS, 256, 0, stream>>>(deg_out, deg_in, onorm, inorm, bsum, N);
  scan2_kernel<<<1, 256, 0, stream>>>(bsum, boff, nbS, row_ptr, N);
  scan3_kernel<<<nbS, 256, 0, stream>>>(deg_in, boff, row_ptr, N);
  fill_kernel<<<(E + 255) / 256, 256, 0, stream>>>(src, dst, w, onorm, inorm, row_ptr,
                                                   rank, col, wse, E);

  dim3 ggrid((N + 127) / 128, 2);       // 391 x 2
  dim3 ggridz((N + 127) / 128, 2, 2);   // 391 x 2 x 2 (z: which GEMM)

  // aggX' = agg(xb)  [norms folded into wse]
  spmm_bf16<0, 1><<<N, 64, 0, stream>>>(xb, 128, row_ptr, col, wse, aggX, 128);
  // z=0: x1 = relu(aggX'@W1) -> x1f1[:,0:256] ; z=1: f1pre = xb@Wfc -> x1f1[:,256:512]
  gemm12_kernel<<<ggridz, 256, 0, stream>>>(aggX, W1t, xb, Wfct, x1f1, N);
  // f1 = relu(LN(f1pre)) in place
  ln_relu_bf16<<<N, 256, 0, stream>>>(x1f1 + 256, 512, gamma, beta);
  // y2 = x1f1 @ W2
  gemm_kernel<<<ggrid, 256, 0, stream>>>(x1f1, 512, W2t, 512, y2, 256, N, 0, 0);
  // x2 = relu(agg'(y2))
  spmm_bf16<1, 2><<<N, 64, 0, stream>>>(y2, 256, row_ptr, col, wse, x2, 256);
  // aggx2 = agg'(x2)
  spmm_bf16<0, 2><<<N, 64, 0, stream>>>(x2, 256, row_ptr, col, wse, aggx2, 256);
  // x3 = relu(aggx2 @ W3) fp32
  gemm_kernel<<<ggrid, 256, 0, stream>>>(aggx2, 256, W3t, 256, x3, 256, N, 1, 1);
  // readout
  readout_kernel<<<dim3(NG, 8), 256, 0, stream>>>(x3, gid, out, N);
}